// Round 6
// baseline (107.229 us; speedup 1.0000x reference)
//
#include <hip/hip_runtime.h>
#include <hip/hip_bf16.h>

typedef __attribute__((ext_vector_type(8))) __bf16 bf16x8;
typedef __attribute__((ext_vector_type(4))) float f32x4;
typedef __attribute__((ext_vector_type(4))) unsigned short u16x4;
typedef unsigned short u16;

typedef __attribute__((address_space(1))) void gvoid;
typedef __attribute__((address_space(3))) void lvoid;

#define B_DIM 8192
#define H_DIM 512

#define MFMA(a, b, c) __builtin_amdgcn_mfma_f32_16x16x32_bf16((a), (b), (c), 0, 0, 0)

__device__ __forceinline__ u16x4 cvt4(f32x4 v) {
    u16x4 r;
    r.x = __builtin_bit_cast(u16, __float2bfloat16(v.x));
    r.y = __builtin_bit_cast(u16, __float2bfloat16(v.y));
    r.z = __builtin_bit_cast(u16, __float2bfloat16(v.z));
    r.w = __builtin_bit_cast(u16, __float2bfloat16(v.w));
    return r;
}

// Stage an R x 64 bf16 tile into LDS (256 threads). LDS dest linear
// (global_load_lds requirement); global SOURCE column pre-permuted so LDS
// slot s of row r holds global slot s^(r&7); readers apply the same XOR
// (ld_frag). [rule #21 both-sides]  Verified: round-3, bank-conflict = 0.
template<int R>
__device__ __forceinline__ void stage_tile(const u16* g, int ldg, u16* ls, int t) {
#pragma unroll
    for (int it = 0; it < R / 32; ++it) {
        int e = it * 2048 + t * 8;
        int r = e >> 6;
        int slot = (e & 63) >> 3;
        int csrc = (slot ^ (r & 7)) << 3;
        __builtin_amdgcn_global_load_lds((gvoid*)(g + (size_t)r * ldg + csrc),
                                         (lvoid*)&ls[e], 16, 0, 0);
    }
}

__device__ __forceinline__ bf16x8 ld_frag(const u16* ls, int row, int kslot) {
    return *(const bf16x8*)&ls[row * 64 + ((kslot ^ (row & 7)) << 3)];
}

// ---------------- all_zero flag + zero class counters ----------------
__global__ void k_flag(const int* __restrict__ pd, int* __restrict__ flag,
                       int* __restrict__ cnt) {
    __shared__ int s;
    if (threadIdx.x == 0) s = 0;
    __syncthreads();
    int any = 0;
    for (int i = threadIdx.x; i < B_DIM; i += 1024) any |= pd[i];
    if (any) atomicOr(&s, 1);
    __syncthreads();
    if (threadIdx.x == 0) {
        flag[0] = (s == 0) ? 1 : 0;
        cnt[0] = 0; cnt[1] = 0; cnt[2] = 0;
    }
}

// ---------------- classify + compact + trivial outputs ----------------
// One wave per row. Classes: 0=NN (needs a00->b00), 1=FN (a10->b10),
// 2=FJ (b11 only; next_a1=pa), 3=COPY (lt: pa/pb1), 4=ZERO (nd>1).
// Compacted A rows: Acls[pos] = [X | second] bf16 (second = pa/pb0/pb1).
__global__ void k_prep3(const float* __restrict__ X, const float* __restrict__ prev_a,
                        const float* __restrict__ prev_b, const int* __restrict__ prev_depth,
                        const float* __restrict__ w_f, const int* __restrict__ flag,
                        int* __restrict__ cnt,
                        u16* __restrict__ Ann, u16* __restrict__ Afn, u16* __restrict__ Afj,
                        int* __restrict__ idx_nn, int* __restrict__ idx_fn, int* __restrict__ idx_fj,
                        float* __restrict__ outA, float* __restrict__ outB,
                        float* __restrict__ outD, float* __restrict__ outF,
                        float* __restrict__ outJ) {
    int wv = threadIdx.x >> 6, l = threadIdx.x & 63;
    int row = blockIdx.x * 4 + wv;
    size_t r512 = (size_t)row * 512, r1024 = (size_t)row * 1024;
    int i = l * 8;
    f32x4 x0  = *(const f32x4*)(X + r512 + i);
    f32x4 x1  = *(const f32x4*)(X + r512 + i + 4);
    f32x4 pa0 = *(const f32x4*)(prev_a + r1024 + 512 + i);
    f32x4 pa1 = *(const f32x4*)(prev_a + r1024 + 512 + i + 4);
    f32x4 q00 = *(const f32x4*)(prev_b + r1024 + i);
    f32x4 q01 = *(const f32x4*)(prev_b + r1024 + i + 4);
    f32x4 q10 = *(const f32x4*)(prev_b + r1024 + 512 + i);
    f32x4 q11 = *(const f32x4*)(prev_b + r1024 + 512 + i + 4);
    f32x4 w0  = *(const f32x4*)(w_f + i);
    f32x4 w1  = *(const f32x4*)(w_f + i + 4);
    int depth = prev_depth[row];
    f32x4 b0 = depth ? q10 : q00;
    f32x4 b1 = depth ? q11 : q01;
    float dot = b0.x*w0.x + b0.y*w0.y + b0.z*w0.z + b0.w*w0.w
              + b1.x*w1.x + b1.y*w1.y + b1.z*w1.z + b1.w*w1.w;
    for (int off = 32; off > 0; off >>= 1) dot += __shfl_xor(dot, off, 64);

    int cls = 0, pos = 0;
    if (l == 0) {
        int az = flag[0];
        float sg = 1.0f / (1.0f + expf(-dot));
        float fr = rintf(sg);
        float f = az ? 1.0f : fr;
        float j = az ? 0.0f : fr;
        int nd = depth + (int)(f - j);
        int eq = (nd == 1), lt = (nd < 1);
        if (eq) cls = (f != 0.0f) ? ((j != 0.0f) ? 2 : 1) : 0;
        else    cls = lt ? 3 : 4;
        if (cls < 3) {
            pos = atomicAdd(&cnt[cls], 1);
            int* ix = (cls == 0) ? idx_nn : (cls == 1) ? idx_fn : idx_fj;
            ix[pos] = row;
        }
        outD[row] = (float)nd;
        outF[row] = f;
        outJ[row] = j;
    }
    cls = __shfl(cls, 0, 64);
    pos = __shfl(pos, 0, 64);

    // zero depth-0 output slabs (always)
    f32x4 z; z.x = 0.f; z.y = 0.f; z.z = 0.f; z.w = 0.f;
    *(f32x4*)(outA + r1024 + i)     = z;
    *(f32x4*)(outA + r1024 + i + 4) = z;
    *(f32x4*)(outB + r1024 + i)     = z;
    *(f32x4*)(outB + r1024 + i + 4) = z;

    if (cls == 0) {                       // NN: A = [X | pa]
        size_t p = (size_t)pos * 1024 + i;
        *(u16x4*)(Ann + p)       = cvt4(x0);
        *(u16x4*)(Ann + p + 4)   = cvt4(x1);
        *(u16x4*)(Ann + p + 512) = cvt4(pa0);
        *(u16x4*)(Ann + p + 516) = cvt4(pa1);
    } else if (cls == 1) {                // FN: A = [X | pb0]
        size_t p = (size_t)pos * 1024 + i;
        *(u16x4*)(Afn + p)       = cvt4(x0);
        *(u16x4*)(Afn + p + 4)   = cvt4(x1);
        *(u16x4*)(Afn + p + 512) = cvt4(q00);
        *(u16x4*)(Afn + p + 516) = cvt4(q01);
    } else if (cls == 2) {                // FJ: A = [X | pb1]; next_a1 = pa
        size_t p = (size_t)pos * 1024 + i;
        *(u16x4*)(Afj + p)       = cvt4(x0);
        *(u16x4*)(Afj + p + 4)   = cvt4(x1);
        *(u16x4*)(Afj + p + 512) = cvt4(q10);
        *(u16x4*)(Afj + p + 516) = cvt4(q11);
        *(f32x4*)(outA + r1024 + 512 + i)     = pa0;
        *(f32x4*)(outA + r1024 + 512 + i + 4) = pa1;
    } else if (cls == 3) {                // COPY: next_a1 = pa, next_b1 = pb1
        *(f32x4*)(outA + r1024 + 512 + i)     = pa0;
        *(f32x4*)(outA + r1024 + 512 + i + 4) = pa1;
        *(f32x4*)(outB + r1024 + 512 + i)     = q10;
        *(f32x4*)(outB + r1024 + 512 + i + 4) = q11;
    } else {                              // ZERO
        *(f32x4*)(outA + r1024 + 512 + i)     = z;
        *(f32x4*)(outA + r1024 + 512 + i + 4) = z;
        *(f32x4*)(outB + r1024 + 512 + i)     = z;
        *(f32x4*)(outB + r1024 + 512 + i + 4) = z;
    }
}

// ---------------- convert all 5 weight matrices to bf16 ----------------
__global__ void k_conv_w(const float* __restrict__ wa00, const float* __restrict__ wa10,
                         const float* __restrict__ wb00, const float* __restrict__ wb11,
                         const float* __restrict__ wb10,
                         u16* __restrict__ oa00, u16* __restrict__ oa10,
                         u16* __restrict__ ob00, u16* __restrict__ ob11,
                         u16* __restrict__ ob10) {
    int t = blockIdx.x * 256 + threadIdx.x;
    const int S  = 512 * 1024 / 4;
    const int SB = 512 * 1536 / 4;
    const float* src; u16* dst; int off;
    if      (t < S)            { src = wa00; dst = oa00; off = t; }
    else if (t < 2 * S)        { src = wa10; dst = oa10; off = t - S; }
    else if (t < 2 * S + SB)   { src = wb00; dst = ob00; off = t - 2 * S; }
    else if (t < 3 * S + SB)   { src = wb11; dst = ob11; off = t - 2 * S - SB; }
    else if (t < 4 * S + SB)   { src = wb10; dst = ob10; off = t - 3 * S - SB; }
    else return;
    f32x4 v = *(const f32x4*)(src + (size_t)off * 4);
    *(u16x4*)(dst + (size_t)off * 4) = cvt4(v);
}

// ---------------- grouped GEMM stage 1: a00(nn), a10(fn), b11(fj) ----------------
// K=1024 for all classes. 64x128 tile, 256 thr (4 waves, 32x64 each).
// Fixed worst-case grid; blocks early-exit past the live tile count.
__global__ __launch_bounds__(256, 4) void k_gemm_s1(
    const u16* __restrict__ Ann, const u16* __restrict__ Afn, const u16* __restrict__ Afj,
    const u16* __restrict__ wa00, const u16* __restrict__ wa10, const u16* __restrict__ wb11,
    const int* __restrict__ idx_nn, const int* __restrict__ idx_fn, const int* __restrict__ idx_fj,
    const int* __restrict__ cnt,
    u16* __restrict__ na1nn, u16* __restrict__ na1fn,
    float* __restrict__ outA, float* __restrict__ outB)
{
    __shared__ u16 lsA[64 * 64];
    __shared__ u16 lsB[128 * 64];
    int c0 = cnt[0], c1 = cnt[1], c2 = cnt[2];
    int t0 = (c0 + 63) >> 6, t1 = (c1 + 63) >> 6, t2 = (c2 + 63) >> 6;
    int L = (int)blockIdx.x;
    int nt = L & 3, T = L >> 2;
    const u16 *A, *W; const int* idx; u16* na1c; int cntc, cls;
    if (T < t0)                { cls = 0; A = Ann; W = wa00; idx = idx_nn; na1c = na1nn; cntc = c0; }
    else if (T < t0 + t1)      { T -= t0; cls = 1; A = Afn; W = wa10; idx = idx_fn; na1c = na1fn; cntc = c1; }
    else if (T < t0 + t1 + t2) { T -= t0 + t1; cls = 2; A = Afj; W = wb11; idx = idx_fj; na1c = nullptr; cntc = c2; }
    else return;
    const int t = threadIdx.x;
    const int m0 = T * 64, n0 = nt * 128;
    const int lane = t & 63, wv = t >> 6;
    const int wr = (wv >> 1) * 32, wc = (wv & 1) * 64;
    const int fr = lane & 15, fq = lane >> 4;

    f32x4 acc[2][4] = {};

    for (int kq = 0; kq < 16; ++kq) {
        int cb = kq * 64;
        stage_tile<64>(A + (size_t)m0 * 1024 + cb, 1024, lsA, t);
        stage_tile<128>(W + (size_t)n0 * 1024 + cb, 1024, lsB, t);
        __syncthreads();
#pragma unroll
        for (int kk = 0; kk < 2; ++kk) {
            int ks = kk * 4 + fq;
            bf16x8 a[2], b[4];
#pragma unroll
            for (int mi = 0; mi < 2; ++mi) a[mi] = ld_frag(lsA, wr + mi * 16 + fr, ks);
#pragma unroll
            for (int ni = 0; ni < 4; ++ni) b[ni] = ld_frag(lsB, wc + ni * 16 + fr, ks);
#pragma unroll
            for (int mi = 0; mi < 2; ++mi)
#pragma unroll
                for (int ni = 0; ni < 4; ++ni)
                    acc[mi][ni] = MFMA(a[mi], b[ni], acc[mi][ni]);
        }
        __syncthreads();
    }

#pragma unroll
    for (int mi = 0; mi < 2; ++mi)
#pragma unroll
        for (int jj = 0; jj < 4; ++jj) {
            int pos = m0 + wr + mi * 16 + fq * 4 + jj;
            if (pos >= cntc) continue;
            int grow = idx[pos];
#pragma unroll
            for (int ni = 0; ni < 4; ++ni) {
                int col = n0 + wc + ni * 16 + fr;
                float v = acc[mi][ni][jj];
                if (cls < 2) {   // na1 for nn/fn rows
                    na1c[(size_t)pos * 512 + col] = __builtin_bit_cast(u16, __float2bfloat16(v));
                    outA[(size_t)grow * 1024 + 512 + col] = v;
                } else {         // fj: next_b1 = b11 product
                    outB[(size_t)grow * 1024 + 512 + col] = v;
                }
            }
        }
}

// ---------------- grouped GEMM stage 2: b00(nn, K=1536), b10(fn, K=1024) ----------------
__global__ __launch_bounds__(256, 4) void k_gemm_s2(
    const u16* __restrict__ Ann, const u16* __restrict__ Afn,
    const u16* __restrict__ na1nn, const u16* __restrict__ na1fn,
    const u16* __restrict__ wb00, const u16* __restrict__ wb10,
    const int* __restrict__ idx_nn, const int* __restrict__ idx_fn,
    const int* __restrict__ cnt,
    float* __restrict__ outB)
{
    __shared__ u16 lsA[64 * 64];
    __shared__ u16 lsB[128 * 64];
    int c0 = cnt[0], c1 = cnt[1];
    int t0 = (c0 + 63) >> 6, t1 = (c1 + 63) >> 6;
    int L = (int)blockIdx.x;
    int nt = L & 3, T = L >> 2;
    int cls, cntc, nkq, Kw;
    const u16 *A0, *A1, *W; const int* idx;
    if (T < t0)           { cls = 0; cntc = c0; nkq = 24; Kw = 1536; A0 = Ann; A1 = na1nn; W = wb00; idx = idx_nn; }
    else if (T < t0 + t1) { T -= t0; cls = 1; cntc = c1; nkq = 16; Kw = 1024; A0 = Afn; A1 = na1fn; W = wb10; idx = idx_fn; }
    else return;
    const int t = threadIdx.x;
    const int m0 = T * 64, n0 = nt * 128;
    const int lane = t & 63, wv = t >> 6;
    const int wr = (wv >> 1) * 32, wc = (wv & 1) * 64;
    const int fr = lane & 15, fq = lane >> 4;
    // class 0: k<1024 from Ann (ld 1024), k>=1024 from na1nn (ld 512)
    // class 1: k<512  from Afn (X half, ld 1024), k>=512 from na1fn (ld 512)
    const int split = (cls == 0) ? 16 : 8;

    f32x4 acc[2][4] = {};

    for (int kq = 0; kq < nkq; ++kq) {
        if (kq < split)
            stage_tile<64>(A0 + (size_t)m0 * 1024 + kq * 64, 1024, lsA, t);
        else
            stage_tile<64>(A1 + (size_t)m0 * 512 + (kq - split) * 64, 512, lsA, t);
        stage_tile<128>(W + (size_t)n0 * Kw + kq * 64, Kw, lsB, t);
        __syncthreads();
#pragma unroll
        for (int kk = 0; kk < 2; ++kk) {
            int ks = kk * 4 + fq;
            bf16x8 a[2], b[4];
#pragma unroll
            for (int mi = 0; mi < 2; ++mi) a[mi] = ld_frag(lsA, wr + mi * 16 + fr, ks);
#pragma unroll
            for (int ni = 0; ni < 4; ++ni) b[ni] = ld_frag(lsB, wc + ni * 16 + fr, ks);
#pragma unroll
            for (int mi = 0; mi < 2; ++mi)
#pragma unroll
                for (int ni = 0; ni < 4; ++ni)
                    acc[mi][ni] = MFMA(a[mi], b[ni], acc[mi][ni]);
        }
        __syncthreads();
    }

#pragma unroll
    for (int mi = 0; mi < 2; ++mi)
#pragma unroll
        for (int jj = 0; jj < 4; ++jj) {
            int pos = m0 + wr + mi * 16 + fq * 4 + jj;
            if (pos >= cntc) continue;
            int grow = idx[pos];
#pragma unroll
            for (int ni = 0; ni < 4; ++ni) {
                int col = n0 + wc + ni * 16 + fr;
                outB[(size_t)grow * 1024 + 512 + col] = acc[mi][ni][jj];
            }
        }
}

extern "C" void kernel_launch(void* const* d_in, const int* in_sizes, int n_in,
                              void* d_out, int out_size, void* d_ws, size_t ws_size,
                              hipStream_t stream) {
    const float* X          = (const float*)d_in[0];
    const float* prev_a     = (const float*)d_in[1];
    const float* prev_b     = (const float*)d_in[2];
    const int*   prev_depth = (const int*)d_in[3];
    const float* w_f        = (const float*)d_in[4];
    const float* w_a00      = (const float*)d_in[5];
    const float* w_a10      = (const float*)d_in[6];
    const float* w_b00      = (const float*)d_in[7];
    const float* w_b11      = (const float*)d_in[8];
    const float* w_b10      = (const float*)d_in[9];

    float* out  = (float*)d_out;
    float* outA = out;
    float* outB = out + 8388608;
    float* outD = out + 16777216;
    float* outF = outD + 8192;
    float* outJ = outF + 8192;

    char* ws = (char*)d_ws;
    size_t off = 0;
    auto alloc = [&](size_t bytes) -> char* {
        char* p = ws + off;
        off += (bytes + 255) & ~(size_t)255;
        return p;
    };
    u16* Ann   = (u16*)alloc((size_t)B_DIM * 1024 * 2);
    u16* Afn   = (u16*)alloc((size_t)B_DIM * 1024 * 2);
    u16* Afj   = (u16*)alloc((size_t)B_DIM * 1024 * 2);
    u16* na1nn = (u16*)alloc((size_t)B_DIM * 512 * 2);
    u16* na1fn = (u16*)alloc((size_t)B_DIM * 512 * 2);
    u16* wa00b = (u16*)alloc((size_t)512 * 1024 * 2);
    u16* wa10b = (u16*)alloc((size_t)512 * 1024 * 2);
    u16* wb00b = (u16*)alloc((size_t)512 * 1536 * 2);
    u16* wb11b = (u16*)alloc((size_t)512 * 1024 * 2);
    u16* wb10b = (u16*)alloc((size_t)512 * 1024 * 2);
    int* idx_nn = (int*)alloc((size_t)B_DIM * 4);
    int* idx_fn = (int*)alloc((size_t)B_DIM * 4);
    int* idx_fj = (int*)alloc((size_t)B_DIM * 4);
    int* cnt    = (int*)alloc(256);
    int* flag   = (int*)alloc(256);
    if (off > ws_size) return;

    k_flag<<<1, 1024, 0, stream>>>(prev_depth, flag, cnt);
    k_prep3<<<2048, 256, 0, stream>>>(X, prev_a, prev_b, prev_depth, w_f, flag, cnt,
                                      Ann, Afn, Afj, idx_nn, idx_fn, idx_fj,
                                      outA, outB, outD, outF, outJ);
    k_conv_w<<<2816, 256, 0, stream>>>(w_a00, w_a10, w_b00, w_b11, w_b10,
                                       wa00b, wa10b, wb00b, wb11b, wb10b);
    // worst case: 8192 rows in one class -> 128 tiles; +2 rounding across classes
    k_gemm_s1<<<131 * 4, 256, 0, stream>>>(Ann, Afn, Afj, wa00b, wa10b, wb11b,
                                           idx_nn, idx_fn, idx_fj, cnt,
                                           na1nn, na1fn, outA, outB);
    k_gemm_s2<<<130 * 4, 256, 0, stream>>>(Ann, Afn, na1nn, na1fn, wb00b, wb10b,
                                           idx_nn, idx_fn, cnt, outB);
}

// Round 7
// 81.731 us; speedup vs baseline: 1.3120x; 1.3120x over previous
//
#include <hip/hip_runtime.h>
#include <hip/hip_bf16.h>

typedef __attribute__((ext_vector_type(8))) __bf16 bf16x8;
typedef __attribute__((ext_vector_type(4))) float f32x4;
typedef __attribute__((ext_vector_type(4))) unsigned short u16x4;
typedef unsigned short u16;

typedef __attribute__((address_space(1))) void gvoid;
typedef __attribute__((address_space(3))) void lvoid;

#define B_DIM 8192
#define MFMA(a, b, c) __builtin_amdgcn_mfma_f32_16x16x32_bf16((a), (b), (c), 0, 0, 0)

__device__ __forceinline__ u16x4 cvt4(f32x4 v) {
    u16x4 r;
    r.x = __builtin_bit_cast(u16, __float2bfloat16(v.x));
    r.y = __builtin_bit_cast(u16, __float2bfloat16(v.y));
    r.z = __builtin_bit_cast(u16, __float2bfloat16(v.z));
    r.w = __builtin_bit_cast(u16, __float2bfloat16(v.w));
    return r;
}

// Stage a 64x64 bf16 tile into LDS (256 threads, 2 x 16B each). LDS dest
// linear (global_load_lds requirement); global SOURCE column pre-permuted so
// LDS slot s of row r holds global slot s^(r&7); readers apply the same XOR
// (ld_frag). [rule #21 both-sides] Verified round-3: bank-conflict = 0.
__device__ __forceinline__ void stage64(const u16* g, int ldg, u16* ls, int t) {
#pragma unroll
    for (int it = 0; it < 2; ++it) {
        int e = it * 2048 + t * 8;
        int r = e >> 6;
        int slot = (e & 63) >> 3;
        int csrc = (slot ^ (r & 7)) << 3;
        __builtin_amdgcn_global_load_lds((gvoid*)(g + (size_t)r * ldg + csrc),
                                         (lvoid*)&ls[e], 16, 0, 0);
    }
}

__device__ __forceinline__ bf16x8 ld_frag(const u16* ls, int row, int kslot) {
    return *(const bf16x8*)&ls[row * 64 + ((kslot ^ (row & 7)) << 3)];
}

// ---------------- 1. per-row gate dot products (pure GEMV) ----------------
__global__ void k_dots(const float* __restrict__ prev_b, const int* __restrict__ prev_depth,
                       const float* __restrict__ w_f, float* __restrict__ dotv) {
    int wv = threadIdx.x >> 6, l = threadIdx.x & 63;
    int row = blockIdx.x * 4 + wv;
    int depth = prev_depth[row];
    const float* bt = prev_b + (size_t)row * 1024 + (size_t)depth * 512;
    int i = l * 8;
    f32x4 v0 = *(const f32x4*)(bt + i);
    f32x4 v1 = *(const f32x4*)(bt + i + 4);
    f32x4 w0 = *(const f32x4*)(w_f + i);
    f32x4 w1 = *(const f32x4*)(w_f + i + 4);
    float dot = v0.x*w0.x + v0.y*w0.y + v0.z*w0.z + v0.w*w0.w
              + v1.x*w1.x + v1.y*w1.y + v1.z*w1.z + v1.w*w1.w;
    for (int off = 32; off > 0; off >>= 1) dot += __shfl_xor(dot, off, 64);
    if (l == 0) dotv[row] = dot;
}

// ---------------- 2. classify + deterministic prefix-sum positions ----------------
// 1 block, 1024 threads, 8 rows/thread. No global atomics: stable (row-ordered)
// positions via 3 block-wide Hillis-Steele scans. cnt[0..2]=counts, cnt[4..6]=bases.
// info[row] = cls | f<<3 | j<<4 | nd<<5 | pos<<7.
__global__ void k_scan(const float* __restrict__ dotv, const int* __restrict__ prev_depth,
                       int* __restrict__ info, int* __restrict__ idx, int* __restrict__ cnt) {
    __shared__ int sh[1024];
    __shared__ int sAny;
    const int tid = threadIdx.x;
    if (tid == 0) sAny = 0;
    __syncthreads();
    int r0 = tid * 8;
    int dep[8]; float dv[8];
    int any = 0;
#pragma unroll
    for (int r = 0; r < 8; ++r) {
        dep[r] = prev_depth[r0 + r];
        dv[r] = dotv[r0 + r];
        any |= dep[r];
    }
    if (any) atomicOr(&sAny, 1);
    __syncthreads();
    int az = (sAny == 0);

    int rcls[8], rf[8], rj[8], rnd[8];
    int c0 = 0, c1 = 0, c2 = 0;
#pragma unroll
    for (int r = 0; r < 8; ++r) {
        float sg = 1.0f / (1.0f + expf(-dv[r]));
        int fi = (int)rintf(sg);           // 0 or 1, round-half-even
        int f = az ? 1 : fi;
        int j = az ? 0 : fi;
        int nd = dep[r] + f - j;
        int cls;
        if (nd == 1)      cls = f ? (j ? 2 : 1) : 0;
        else if (nd < 1)  cls = 3;
        else              cls = 4;
        rcls[r] = cls; rf[r] = f; rj[r] = j; rnd[r] = nd;
        if (cls == 0) c0++; else if (cls == 1) c1++; else if (cls == 2) c2++;
    }

    int excl0, excl1, excl2, tot0, tot1, tot2;
#pragma unroll
    for (int ci = 0; ci < 3; ++ci) {
        int myc = (ci == 0) ? c0 : (ci == 1) ? c1 : c2;
        __syncthreads();
        sh[tid] = myc;
        __syncthreads();
        for (int off = 1; off < 1024; off <<= 1) {
            int v = (tid >= off) ? sh[tid - off] : 0;
            __syncthreads();
            sh[tid] += v;
            __syncthreads();
        }
        int e = sh[tid] - myc, tt = sh[1023];
        if (ci == 0) { excl0 = e; tot0 = tt; }
        else if (ci == 1) { excl1 = e; tot1 = tt; }
        else { excl2 = e; tot2 = tt; }
    }
    int base0 = 0;
    int base1 = (tot0 + 63) & ~63;
    int base2 = base1 + ((tot1 + 63) & ~63);
    int o0 = base0 + excl0, o1 = base1 + excl1, o2 = base2 + excl2;
#pragma unroll
    for (int r = 0; r < 8; ++r) {
        int row = r0 + r, cls = rcls[r], pos = 0;
        if (cls == 0)      { pos = o0++; idx[pos] = row; }
        else if (cls == 1) { pos = o1++; idx[pos] = row; }
        else if (cls == 2) { pos = o2++; idx[pos] = row; }
        info[row] = cls | (rf[r] << 3) | (rj[r] << 4) | (rnd[r] << 5) | (pos << 7);
    }
    if (tid == 0) {
        cnt[0] = tot0; cnt[1] = tot1; cnt[2] = tot2;
        cnt[4] = base0; cnt[5] = base1; cnt[6] = base2;
    }
}

// ---------------- 3. streaming compact + trivial outputs + weight conversion ----------------
// blocks [0,2048): 4 waves, one row each. blocks [2048,4864): weight bf16 conversion.
__global__ void k_compact(const float* __restrict__ X, const float* __restrict__ prev_a,
                          const float* __restrict__ prev_b,
                          const float* __restrict__ wa00f, const float* __restrict__ wa10f,
                          const float* __restrict__ wb00f, const float* __restrict__ wb11f,
                          const float* __restrict__ wb10f,
                          const int* __restrict__ info,
                          u16* __restrict__ A_all,
                          u16* __restrict__ wa00b, u16* __restrict__ wa10b,
                          u16* __restrict__ wb00b, u16* __restrict__ wb11b,
                          u16* __restrict__ wb10b,
                          float* __restrict__ outA, float* __restrict__ outB,
                          float* __restrict__ outD, float* __restrict__ outF,
                          float* __restrict__ outJ) {
    int blk = blockIdx.x;
    if (blk >= 2048) {
        int t = (blk - 2048) * 256 + threadIdx.x;
        const int S = 131072, SB = 196608;
        const float* src; u16* dst; int off;
        if      (t < S)            { src = wa00f; dst = wa00b; off = t; }
        else if (t < 2 * S)        { src = wa10f; dst = wa10b; off = t - S; }
        else if (t < 2 * S + SB)   { src = wb00f; dst = wb00b; off = t - 2 * S; }
        else if (t < 3 * S + SB)   { src = wb11f; dst = wb11b; off = t - 2 * S - SB; }
        else if (t < 4 * S + SB)   { src = wb10f; dst = wb10b; off = t - 3 * S - SB; }
        else return;
        f32x4 v = *(const f32x4*)(src + (size_t)off * 4);
        *(u16x4*)(dst + (size_t)off * 4) = cvt4(v);
        return;
    }
    int wv = threadIdx.x >> 6, l = threadIdx.x & 63;
    int row = blk * 4 + wv;
    int inf = info[row];
    int cls = inf & 7;
    int pos = inf >> 7;
    size_t r512 = (size_t)row * 512, r1024 = (size_t)row * 1024;
    int i = l * 8;
    f32x4 x0  = *(const f32x4*)(X + r512 + i);
    f32x4 x1  = *(const f32x4*)(X + r512 + i + 4);
    f32x4 pa0 = *(const f32x4*)(prev_a + r1024 + 512 + i);
    f32x4 pa1 = *(const f32x4*)(prev_a + r1024 + 512 + i + 4);
    f32x4 q10 = *(const f32x4*)(prev_b + r1024 + 512 + i);
    f32x4 q11 = *(const f32x4*)(prev_b + r1024 + 512 + i + 4);
    f32x4 z; z.x = 0.f; z.y = 0.f; z.z = 0.f; z.w = 0.f;
    *(f32x4*)(outA + r1024 + i)     = z;
    *(f32x4*)(outA + r1024 + i + 4) = z;
    *(f32x4*)(outB + r1024 + i)     = z;
    *(f32x4*)(outB + r1024 + i + 4) = z;
    if (l == 0) {
        outD[row] = (float)((inf >> 5) & 3);
        outF[row] = (float)((inf >> 3) & 1);
        outJ[row] = (float)((inf >> 4) & 1);
    }
    if (cls == 0) {                       // NN: A = [X | pa]
        size_t p = (size_t)pos * 1024 + i;
        *(u16x4*)(A_all + p)       = cvt4(x0);
        *(u16x4*)(A_all + p + 4)   = cvt4(x1);
        *(u16x4*)(A_all + p + 512) = cvt4(pa0);
        *(u16x4*)(A_all + p + 516) = cvt4(pa1);
    } else if (cls == 1) {                // FN: A = [X | pb0]
        f32x4 q00 = *(const f32x4*)(prev_b + r1024 + i);
        f32x4 q01 = *(const f32x4*)(prev_b + r1024 + i + 4);
        size_t p = (size_t)pos * 1024 + i;
        *(u16x4*)(A_all + p)       = cvt4(x0);
        *(u16x4*)(A_all + p + 4)   = cvt4(x1);
        *(u16x4*)(A_all + p + 512) = cvt4(q00);
        *(u16x4*)(A_all + p + 516) = cvt4(q01);
    } else if (cls == 2) {                // FJ: A = [X | pb1]; next_a1 = pa
        size_t p = (size_t)pos * 1024 + i;
        *(u16x4*)(A_all + p)       = cvt4(x0);
        *(u16x4*)(A_all + p + 4)   = cvt4(x1);
        *(u16x4*)(A_all + p + 512) = cvt4(q10);
        *(u16x4*)(A_all + p + 516) = cvt4(q11);
        *(f32x4*)(outA + r1024 + 512 + i)     = pa0;
        *(f32x4*)(outA + r1024 + 512 + i + 4) = pa1;
    } else if (cls == 3) {                // COPY
        *(f32x4*)(outA + r1024 + 512 + i)     = pa0;
        *(f32x4*)(outA + r1024 + 512 + i + 4) = pa1;
        *(f32x4*)(outB + r1024 + 512 + i)     = q10;
        *(f32x4*)(outB + r1024 + 512 + i + 4) = q11;
    } else {                              // ZERO
        *(f32x4*)(outA + r1024 + 512 + i)     = z;
        *(f32x4*)(outA + r1024 + 512 + i + 4) = z;
        *(f32x4*)(outB + r1024 + 512 + i)     = z;
        *(f32x4*)(outB + r1024 + 512 + i + 4) = z;
    }
}

// ---------------- 4. grouped GEMM stage 1 (dual-acc: A-reuse for b-partials) ----
// nn: a00=[X|pa]@wa00 AND part=[X|pa]@wb00[:,:1024]; fn: a10 AND part=X@wb10[:,:512];
// fj: b11 only. 64x64 tiles, 4 waves (2x2, 32x32 each), grid 8x130 XCD-swizzled.
__global__ __launch_bounds__(256, 4) void k_s1(
    const u16* __restrict__ A_all,
    const u16* __restrict__ wa00, const u16* __restrict__ wa10,
    const u16* __restrict__ wb00, const u16* __restrict__ wb11,
    const u16* __restrict__ wb10,
    const int* __restrict__ idx, const int* __restrict__ cnt,
    u16* __restrict__ na1_all, float* __restrict__ part,
    float* __restrict__ outA, float* __restrict__ outB)
{
    __shared__ u16 lsA[4096], lsB0[4096], lsB1[4096];
    int c0 = cnt[0], c1 = cnt[1], c2 = cnt[2];
    int base0 = cnt[4], base1 = cnt[5], base2 = cnt[6];
    int t0 = (c0 + 63) >> 6, t1 = (c1 + 63) >> 6, t2 = (c2 + 63) >> 6;
    int raw = (int)blockIdx.x;
    int swz = (raw & 7) * 130 + (raw >> 3);   // bijective: 1040 = 8*130
    int T = swz >> 3, nt = swz & 7;
    int cls, mb, cc;
    const u16 *W0, *W1 = nullptr;
    int ldW1 = 0;
    if (T < t0)                { cls = 0; mb = base0 + T * 64; cc = c0; W0 = wa00; W1 = wb00; ldW1 = 1536; }
    else if (T < t0 + t1)      { T -= t0; cls = 1; mb = base1 + T * 64; cc = c1; W0 = wa10; W1 = wb10; ldW1 = 1024; }
    else if (T < t0 + t1 + t2) { T -= t0 + t1; cls = 2; mb = base2 + T * 64; cc = c2; W0 = wb11; }
    else return;
    const int t = threadIdx.x;
    const int n0 = nt * 64;
    const int lane = t & 63, wv = t >> 6;
    const int wr = (wv >> 1) * 32, wc = (wv & 1) * 32;
    const int fr = lane & 15, fq = lane >> 4;

    f32x4 acc0[2][2] = {}, acc1[2][2] = {};

    for (int kq = 0; kq < 16; ++kq) {
        int cb = kq * 64;
        stage64(A_all + (size_t)mb * 1024 + cb, 1024, lsA, t);
        stage64(W0 + (size_t)n0 * 1024 + cb, 1024, lsB0, t);
        bool dual = (cls == 0) || (cls == 1 && kq < 8);
        if (dual) stage64(W1 + (size_t)n0 * ldW1 + cb, ldW1, lsB1, t);
        __syncthreads();
#pragma unroll
        for (int kk = 0; kk < 2; ++kk) {
            int ks = kk * 4 + fq;
            bf16x8 a[2], b0[2], b1[2];
#pragma unroll
            for (int mi = 0; mi < 2; ++mi) a[mi] = ld_frag(lsA, wr + mi * 16 + fr, ks);
#pragma unroll
            for (int ni = 0; ni < 2; ++ni) b0[ni] = ld_frag(lsB0, wc + ni * 16 + fr, ks);
            if (dual) {
#pragma unroll
                for (int ni = 0; ni < 2; ++ni) b1[ni] = ld_frag(lsB1, wc + ni * 16 + fr, ks);
            }
#pragma unroll
            for (int mi = 0; mi < 2; ++mi)
#pragma unroll
                for (int ni = 0; ni < 2; ++ni) {
                    acc0[mi][ni] = MFMA(a[mi], b0[ni], acc0[mi][ni]);
                    if (dual) acc1[mi][ni] = MFMA(a[mi], b1[ni], acc1[mi][ni]);
                }
        }
        __syncthreads();
    }
    int lt0 = T * 64;
#pragma unroll
    for (int mi = 0; mi < 2; ++mi)
#pragma unroll
        for (int jj = 0; jj < 4; ++jj) {
            int lr = wr + mi * 16 + fq * 4 + jj;
            if (lt0 + lr >= cc) continue;
            int grow = idx[mb + lr];
#pragma unroll
            for (int ni = 0; ni < 2; ++ni) {
                int col = n0 + wc + ni * 16 + fr;
                float v = acc0[mi][ni][jj];
                if (cls < 2) {
                    na1_all[(size_t)(mb + lr) * 512 + col] = __builtin_bit_cast(u16, __float2bfloat16(v));
                    outA[(size_t)grow * 1024 + 512 + col] = v;
                    part[(size_t)(mb + lr) * 512 + col] = acc1[mi][ni][jj];
                } else {
                    outB[(size_t)grow * 1024 + 512 + col] = v;
                }
            }
        }
}

// ---------------- 5. grouped GEMM stage 2: K=512 tail + partial init ----------------
__global__ __launch_bounds__(256, 4) void k_s2(
    const u16* __restrict__ na1_all,
    const u16* __restrict__ wb00, const u16* __restrict__ wb10,
    const int* __restrict__ idx, const int* __restrict__ cnt,
    const float* __restrict__ part, float* __restrict__ outB)
{
    __shared__ u16 lsA[4096], lsB[4096];
    int c0 = cnt[0], c1 = cnt[1];
    int base0 = cnt[4], base1 = cnt[5];
    int t0 = (c0 + 63) >> 6, t1 = (c1 + 63) >> 6;
    int raw = (int)blockIdx.x;
    int swz = (raw & 7) * 130 + (raw >> 3);
    int T = swz >> 3, nt = swz & 7;
    int cls, mb, cc, ldW, kofs;
    const u16* W;
    if (T < t0)           { cls = 0; mb = base0 + T * 64; cc = c0; W = wb00; ldW = 1536; kofs = 1024; }
    else if (T < t0 + t1) { T -= t0; cls = 1; mb = base1 + T * 64; cc = c1; W = wb10; ldW = 1024; kofs = 512; }
    else return;
    const int t = threadIdx.x;
    const int n0 = nt * 64;
    const int lane = t & 63, wv = t >> 6;
    const int wr = (wv >> 1) * 32, wc = (wv & 1) * 32;
    const int fr = lane & 15, fq = lane >> 4;

    f32x4 acc[2][2];
#pragma unroll
    for (int mi = 0; mi < 2; ++mi)
#pragma unroll
        for (int ni = 0; ni < 2; ++ni)
#pragma unroll
            for (int jj = 0; jj < 4; ++jj)
                acc[mi][ni][jj] = part[(size_t)(mb + wr + mi * 16 + fq * 4 + jj) * 512
                                       + n0 + wc + ni * 16 + fr];

    for (int kq = 0; kq < 8; ++kq) {
        stage64(na1_all + (size_t)mb * 512 + kq * 64, 512, lsA, t);
        stage64(W + (size_t)n0 * ldW + kofs + kq * 64, ldW, lsB, t);
        __syncthreads();
#pragma unroll
        for (int kk = 0; kk < 2; ++kk) {
            int ks = kk * 4 + fq;
            bf16x8 a[2], b[2];
#pragma unroll
            for (int mi = 0; mi < 2; ++mi) a[mi] = ld_frag(lsA, wr + mi * 16 + fr, ks);
#pragma unroll
            for (int ni = 0; ni < 2; ++ni) b[ni] = ld_frag(lsB, wc + ni * 16 + fr, ks);
#pragma unroll
            for (int mi = 0; mi < 2; ++mi)
#pragma unroll
                for (int ni = 0; ni < 2; ++ni)
                    acc[mi][ni] = MFMA(a[mi], b[ni], acc[mi][ni]);
        }
        __syncthreads();
    }
    int lt0 = T * 64;
#pragma unroll
    for (int mi = 0; mi < 2; ++mi)
#pragma unroll
        for (int jj = 0; jj < 4; ++jj) {
            int lr = wr + mi * 16 + fq * 4 + jj;
            if (lt0 + lr >= cc) continue;
            int grow = idx[mb + lr];
#pragma unroll
            for (int ni = 0; ni < 2; ++ni) {
                int col = n0 + wc + ni * 16 + fr;
                outB[(size_t)grow * 1024 + 512 + col] = acc[mi][ni][jj];
            }
        }
}

extern "C" void kernel_launch(void* const* d_in, const int* in_sizes, int n_in,
                              void* d_out, int out_size, void* d_ws, size_t ws_size,
                              hipStream_t stream) {
    const float* X          = (const float*)d_in[0];
    const float* prev_a     = (const float*)d_in[1];
    const float* prev_b     = (const float*)d_in[2];
    const int*   prev_depth = (const int*)d_in[3];
    const float* w_f        = (const float*)d_in[4];
    const float* w_a00      = (const float*)d_in[5];
    const float* w_a10      = (const float*)d_in[6];
    const float* w_b00      = (const float*)d_in[7];
    const float* w_b11      = (const float*)d_in[8];
    const float* w_b10      = (const float*)d_in[9];

    float* out  = (float*)d_out;
    float* outA = out;
    float* outB = out + 8388608;
    float* outD = out + 16777216;
    float* outF = outD + 8192;
    float* outJ = outF + 8192;

    char* ws = (char*)d_ws;
    size_t off = 0;
    auto alloc = [&](size_t bytes) -> char* {
        char* p = ws + off;
        off += (bytes + 255) & ~(size_t)255;
        return p;
    };
    const int ROWS = 8448;   // 8192 + 2x64-alignment slack
    u16* A_all    = (u16*)alloc((size_t)ROWS * 1024 * 2);
    u16* na1_all  = (u16*)alloc((size_t)ROWS * 512 * 2);
    float* part   = (float*)alloc((size_t)ROWS * 512 * 4);
    u16* wa00b = (u16*)alloc((size_t)512 * 1024 * 2);
    u16* wa10b = (u16*)alloc((size_t)512 * 1024 * 2);
    u16* wb00b = (u16*)alloc((size_t)512 * 1536 * 2);
    u16* wb11b = (u16*)alloc((size_t)512 * 1024 * 2);
    u16* wb10b = (u16*)alloc((size_t)512 * 1024 * 2);
    float* dotv = (float*)alloc((size_t)B_DIM * 4);
    int* info   = (int*)alloc((size_t)B_DIM * 4);
    int* idx    = (int*)alloc((size_t)ROWS * 4);
    int* cnt    = (int*)alloc(256);
    if (off > ws_size) return;

    k_dots<<<2048, 256, 0, stream>>>(prev_b, prev_depth, w_f, dotv);
    k_scan<<<1, 1024, 0, stream>>>(dotv, prev_depth, info, idx, cnt);
    k_compact<<<4864, 256, 0, stream>>>(X, prev_a, prev_b,
                                        w_a00, w_a10, w_b00, w_b11, w_b10,
                                        info, A_all,
                                        wa00b, wa10b, wb00b, wb11b, wb10b,
                                        outA, outB, outD, outF, outJ);
    k_s1<<<1040, 256, 0, stream>>>(A_all, wa00b, wa10b, wb00b, wb11b, wb10b,
                                   idx, cnt, na1_all, part, outA, outB);
    k_s2<<<1040, 256, 0, stream>>>(na1_all, wb00b, wb10b, idx, cnt, part, outB);
}